// Round 2
// baseline (842.447 us; speedup 1.0000x reference)
//
#include <hip/hip_runtime.h>
#include <hip/hip_bf16.h>
#include <math.h>

// Problem dims (fixed): B*T=32, N=8192, F0=4, F1=8, F2=8, K=3, D0=8, D1=4
constexpr int NN = 8192;

typedef short bh8 __attribute__((ext_vector_type(8)));    // 8 bf16 (4 VGPRs)
typedef float fl4 __attribute__((ext_vector_type(4)));    // 4 fp32 acc

__device__ __forceinline__ float bf2f(ushort h) {
  return __uint_as_float(((uint)h) << 16);
}
__device__ __forceinline__ ushort f2bf(float f) {
  uint u = __float_as_uint(f);
  return (ushort)((u + 0x7fffu + ((u >> 16) & 1u)) >> 16);  // RNE
}

// ---- workspace layout (bytes) ----------------------------------------------
constexpr size_t OFF_P  = 16;        // 412 floats of canonical fp32 params
constexpr size_t OFF_XC = 4096;      // canonical bf16 x  [128][8192]  2 MiB
constexpr size_t OFF_Z1 = OFF_XC + 2097152;   // z1 bf16 [128][8192]
constexpr size_t OFF_Z2 = OFF_Z1 + 2097152;   // z2 bf16 [128][8192]
constexpr size_t OFF_Y1 = OFF_Z2 + 2097152;   // y1 bf16 [256][8192]
constexpr size_t OFF_V1 = OFF_Y1 + 4194304;   // v1 bf16 [256][8192]
constexpr size_t OFF_V2 = OFF_V1 + 4194304;   // v2 bf16 [256][8192]
// total = 4096 + 18 MiB  (~18.9 MB)

// param-block offsets (in floats)
constexpr int PO_H1 = 0, PO_B1 = 96, PO_H2 = 104, PO_B2 = 296;
constexpr int PO_W1 = 304, PO_BW1 = 368, PO_W2 = 376, PO_BW2 = 408;

// ---------------------------------------------------------------------------
// detect dtype (fp32 vs bf16) from S's raw bytes; canonicalize params to fp32.
// Even-index ushorts of an fp32 buffer are mantissa noise (exponent field
// uniform 0..255); genuine bf16 S ~ N(0, 1/90) has exponent <= ~0x7B.
// ---------------------------------------------------------------------------
__global__ __launch_bounds__(256) void detect_convert(
    const ushort* __restrict__ Sraw,
    const void* h1, const void* b1, const void* h2, const void* b2,
    const void* W1, const void* bw1, const void* W2, const void* bw2,
    char* __restrict__ ws) {
  __shared__ int smax[256];
  __shared__ int sflag;
  const int t = threadIdx.x;
  int mx = 0;
  for (int k = 0; k < 32; ++k) {
    ushort u = Sraw[(size_t)(t * 32 + k) * 2];
    int e = (u >> 7) & 0xff;
    mx = mx > e ? mx : e;
  }
  smax[t] = mx;
  __syncthreads();
  for (int s = 128; s > 0; s >>= 1) {
    if (t < s) smax[t] = smax[t] > smax[t + s] ? smax[t] : smax[t + s];
    __syncthreads();
  }
  if (t == 0) {
    sflag = (smax[0] >= 0x90) ? 1 : 0;
    *(int*)ws = sflag;
  }
  __syncthreads();
  const int f32 = sflag;
  float* pb = (float*)(ws + OFF_P);
  const void* ptrs[8] = {h1, b1, h2, b2, W1, bw1, W2, bw2};
  const int offs[8] = {PO_H1, PO_B1, PO_H2, PO_B2, PO_W1, PO_BW1, PO_W2, PO_BW2};
  const int lens[8] = {96, 8, 192, 8, 64, 8, 32, 4};
  for (int idx = t; idx < 412; idx += 256) {
#pragma unroll
    for (int s = 0; s < 8; ++s) {
      if (idx >= offs[s] && idx < offs[s] + lens[s]) {
        const int j = idx - offs[s];
        pb[idx] = f32 ? ((const float*)ptrs[s])[j]
                      : bf2f(((const ushort*)ptrs[s])[j]);
      }
    }
  }
}

// canonicalize x -> bf16 (1,048,576 elements; 4 per thread, 1024 blocks)
__global__ __launch_bounds__(256) void convert_x(const void* __restrict__ xraw,
                                                 const char* __restrict__ wsro,
                                                 ushort* __restrict__ xc) {
  const int f32 = *(const int*)wsro;
  const int i = (blockIdx.x * 256 + threadIdx.x) * 4;
  if (f32) {
    float4 v = *(const float4*)((const float*)xraw + i);
    uint2 o;
    o.x = (uint)f2bf(v.x) | ((uint)f2bf(v.y) << 16);
    o.y = (uint)f2bf(v.z) | ((uint)f2bf(v.w) << 16);
    *(uint2*)&xc[i] = o;
  } else {
    *(uint2*)&xc[i] = *(const uint2*)((const ushort*)xraw + i);
  }
}

// ---------------------------------------------------------------------------
// GEMM: C[M,N] = A[M,K] @ S[K,N]  (A canonical bf16 row-major; S raw, either
// dtype, row-major along N). S tile is transposed in LDS: each thread loads a
// k-pair x 8 nodes, packs into uints (lo=k even, hi=k odd), and scatters with
// a 3-term XOR swizzle -> both the b32 writes and the b128 fragment reads are
// 2-way-per-bank (free). A tile staged via uint4 -> ds_write_b128, source-side
// XOR swizzle g^(row&7) for conflict-free b128 fragment reads.
// 256 threads = 4 waves in 2x2; 16x16x32 bf16 MFMA, fp32 accumulate.
// ---------------------------------------------------------------------------
template <int BM, int TM, int TN>
__global__ __launch_bounds__(256) void gemm_s(const ushort* __restrict__ A,
                                              const ushort* __restrict__ Sraw,
                                              const char* __restrict__ wsro,
                                              ushort* __restrict__ C) {
  constexpr int BK = 64, BN = 64;
  constexpr int A_INST = (BM * 8) / 256;
  static_assert(TM * 16 * 2 == BM && TN * 16 * 2 == BN, "wave layout 2x2");
  __shared__ ushort As[BM * BK];
  __shared__ uint BsU[BN * 32];        // [n][32 kpairs], swizzled granules
  const int f32 = *(const int*)wsro;
  const int tid = threadIdx.x;
  const int wave = tid >> 6, lane = tid & 63;
  const int lrow = lane & 15, quad = lane >> 4;
  const int m0 = blockIdx.y * BM, n0 = blockIdx.x * BN;
  const int wm = (wave & 1) * (TM * 16);
  const int wn = (wave >> 1) * (TN * 16);
  // B-staging thread map: kpair p (0..31), column octet cb (0..7)
  const int p = tid >> 3;
  const int cb = tid & 7;
  const int c = cb * 8;

  fl4 acc[TM][TN];
#pragma unroll
  for (int i = 0; i < TM; ++i)
#pragma unroll
    for (int j = 0; j < TN; ++j) acc[i][j] = (fl4){0.f, 0.f, 0.f, 0.f};

  for (int k0 = 0; k0 < NN; k0 += BK) {
    __syncthreads();
    // ---- stage A tile (canonical bf16): slot s holds row=s>>3, group g=(s&7)^(row&7)
#pragma unroll
    for (int i = 0; i < A_INST; ++i) {
      const int s = (i * 4 + wave) * 64 + lane;
      const int row = s >> 3;
      const int g = (s & 7) ^ (row & 7);
      uint4 v = *(const uint4*)&A[(size_t)(m0 + row) * NN + k0 + g * 8];
      *(uint4*)&As[s * 8] = v;
    }
    // ---- stage S tile transposed: rows k0+2p, k0+2p+1, cols n0+c..c+7
    uint pk[8];
    if (f32) {
      const float* r0 = (const float*)Sraw + (size_t)(k0 + 2 * p) * NN + n0 + c;
      float4 a0 = *(const float4*)r0;
      float4 a1 = *(const float4*)(r0 + 4);
      float4 b0 = *(const float4*)(r0 + NN);
      float4 b1 = *(const float4*)(r0 + NN + 4);
      pk[0] = (uint)f2bf(a0.x) | ((uint)f2bf(b0.x) << 16);
      pk[1] = (uint)f2bf(a0.y) | ((uint)f2bf(b0.y) << 16);
      pk[2] = (uint)f2bf(a0.z) | ((uint)f2bf(b0.z) << 16);
      pk[3] = (uint)f2bf(a0.w) | ((uint)f2bf(b0.w) << 16);
      pk[4] = (uint)f2bf(a1.x) | ((uint)f2bf(b1.x) << 16);
      pk[5] = (uint)f2bf(a1.y) | ((uint)f2bf(b1.y) << 16);
      pk[6] = (uint)f2bf(a1.z) | ((uint)f2bf(b1.z) << 16);
      pk[7] = (uint)f2bf(a1.w) | ((uint)f2bf(b1.w) << 16);
    } else {
      const ushort* r0 = Sraw + (size_t)(k0 + 2 * p) * NN + n0 + c;
      uint4 ua = *(const uint4*)r0;
      uint4 ub = *(const uint4*)(r0 + NN);
      const ushort* ap = (const ushort*)&ua;
      const ushort* bp = (const ushort*)&ub;
#pragma unroll
      for (int j = 0; j < 8; ++j) pk[j] = (uint)ap[j] | ((uint)bp[j] << 16);
    }
#pragma unroll
    for (int j = 0; j < 8; ++j) {
      const int nl = c + j;
      const int q = (p >> 2) ^ (nl & 7) ^ cb;     // cb == nl>>3
      BsU[nl * 32 + q * 4 + (p & 3)] = pk[j];
    }
    __syncthreads();
    // ---- compute: 2 k-subchunks of 32
#pragma unroll
    for (int ks = 0; ks < 2; ++ks) {
      bh8 af[TM], bf[TN];
      const int G = ks * 4 + quad;
#pragma unroll
      for (int i = 0; i < TM; ++i) {
        const int row = wm + i * 16 + lrow;
        const int gs = G ^ (row & 7);
        af[i] = *(const bh8*)&As[row * BK + gs * 8];
      }
#pragma unroll
      for (int j = 0; j < TN; ++j) {
        const int nl = wn + j * 16 + lrow;
        const int q = G ^ (nl & 7) ^ ((nl >> 3) & 7);
        bf[j] = *(const bh8*)&BsU[nl * 32 + q * 4];
      }
#pragma unroll
      for (int i = 0; i < TM; ++i)
#pragma unroll
        for (int j = 0; j < TN; ++j)
          acc[i][j] = __builtin_amdgcn_mfma_f32_16x16x32_bf16(af[i], bf[j],
                                                              acc[i][j], 0, 0, 0);
    }
  }
  // ---- epilogue: C/D layout col=lane&15, row=quad*4+reg
#pragma unroll
  for (int i = 0; i < TM; ++i)
#pragma unroll
    for (int j = 0; j < TN; ++j)
#pragma unroll
      for (int r = 0; r < 4; ++r) {
        const int row = m0 + wm + i * 16 + quad * 4 + r;
        const int col = n0 + wn + j * 16 + lrow;
        C[(size_t)row * NN + col] = f2bf(acc[i][j][r]);
      }
}

// ---------------------------------------------------------------------------
// combine1: y1[bt,g,n] = tanh(b1[g] + sum_{k,f} h1[g,k,f] * z_k[bt,f,n])
// taps z0=xc, z1, z2 all canonical bf16. 4 nodes per thread.
// ---------------------------------------------------------------------------
__global__ __launch_bounds__(256) void combine1(const ushort* __restrict__ xc,
                                                const ushort* __restrict__ z1,
                                                const ushort* __restrict__ z2,
                                                const char* __restrict__ wsro,
                                                ushort* __restrict__ y1) {
  const float* pb = (const float*)(wsro + OFF_P);
  __shared__ float hs[96], bs[8];
  const int t = threadIdx.x;
  if (t < 96) hs[t] = pb[PO_H1 + t];
  if (t < 8) bs[t] = pb[PO_B1 + t];
  __syncthreads();
  const int idx = blockIdx.x * 256 + t;
  const int bt = idx >> 11;
  const int n4 = (idx & 2047) * 4;
  float acc[8][4];
#pragma unroll
  for (int g = 0; g < 8; ++g)
#pragma unroll
    for (int v = 0; v < 4; ++v) acc[g][v] = bs[g];
  const ushort* taps[3] = {xc, z1, z2};
#pragma unroll
  for (int k = 0; k < 3; ++k)
#pragma unroll
    for (int f = 0; f < 4; ++f) {
      const size_t off = (size_t)(bt * 4 + f) * NN + n4;
      uint2 w = *(const uint2*)&taps[k][off];
      float val[4] = {bf2f(w.x & 0xffff), bf2f(w.x >> 16),
                      bf2f(w.y & 0xffff), bf2f(w.y >> 16)};
#pragma unroll
      for (int g = 0; g < 8; ++g) {
        const float hw = hs[(g * 3 + k) * 4 + f];
#pragma unroll
        for (int v = 0; v < 4; ++v) acc[g][v] += hw * val[v];
      }
    }
#pragma unroll
  for (int g = 0; g < 8; ++g) {
    ushort o[4];
#pragma unroll
    for (int v = 0; v < 4; ++v) o[v] = f2bf(tanhf(acc[g][v]));
    uint2 w;
    w.x = (uint)o[0] | ((uint)o[1] << 16);
    w.y = (uint)o[2] | ((uint)o[3] << 16);
    *(uint2*)&y1[(size_t)(bt * 8 + g) * NN + n4] = w;
  }
}

// ---------------------------------------------------------------------------
// combine2: y2 = tanh(b2 + sum h2*{y1,v1,v2}); readout W1/tanh/W2; store out
// in the detected dtype. 2 nodes per thread.
// ---------------------------------------------------------------------------
__global__ __launch_bounds__(256) void combine2(const ushort* __restrict__ y1,
                                                const ushort* __restrict__ v1,
                                                const ushort* __restrict__ v2,
                                                const char* __restrict__ wsro,
                                                void* __restrict__ outv) {
  const float* pb = (const float*)(wsro + OFF_P);
  const int f32 = *(const int*)wsro;
  __shared__ float h2s[192], W1s[64], W2s[32], b2s[8], bw1s[8], bw2s[4];
  const int t = threadIdx.x;
  if (t < 192) h2s[t] = pb[PO_H2 + t];
  if (t < 64) W1s[t] = pb[PO_W1 + t];
  if (t < 32) W2s[t] = pb[PO_W2 + t];
  if (t < 8) { b2s[t] = pb[PO_B2 + t]; bw1s[t] = pb[PO_BW1 + t]; }
  if (t < 4) bw2s[t] = pb[PO_BW2 + t];
  __syncthreads();
  const int idx = blockIdx.x * 256 + t;
  const int bt = idx >> 12;
  const int n2 = (idx & 4095) * 2;
  float acc[8][2];
#pragma unroll
  for (int g = 0; g < 8; ++g) { acc[g][0] = b2s[g]; acc[g][1] = b2s[g]; }
  const ushort* taps[3] = {y1, v1, v2};
#pragma unroll
  for (int k = 0; k < 3; ++k)
#pragma unroll
    for (int g1 = 0; g1 < 8; ++g1) {
      uint w = *(const uint*)&taps[k][(size_t)(bt * 8 + g1) * NN + n2];
      const float v0 = bf2f(w & 0xffff), v1v = bf2f(w >> 16);
#pragma unroll
      for (int g2 = 0; g2 < 8; ++g2) {
        const float hw = h2s[(g2 * 3 + k) * 8 + g1];
        acc[g2][0] += hw * v0;
        acc[g2][1] += hw * v1v;
      }
    }
#pragma unroll
  for (int g = 0; g < 8; ++g) {
    acc[g][0] = tanhf(acc[g][0]);
    acc[g][1] = tanhf(acc[g][1]);
  }
  float o[4][2];
#pragma unroll
  for (int e = 0; e < 4; ++e) { o[e][0] = bw2s[e]; o[e][1] = bw2s[e]; }
#pragma unroll
  for (int d = 0; d < 8; ++d) {
    float s0 = bw1s[d], s1 = bw1s[d];
#pragma unroll
    for (int f = 0; f < 8; ++f) {
      const float w = W1s[d * 8 + f];
      s0 += w * acc[f][0];
      s1 += w * acc[f][1];
    }
    s0 = tanhf(s0);
    s1 = tanhf(s1);
#pragma unroll
    for (int e = 0; e < 4; ++e) {
      const float w = W2s[e * 8 + d];
      o[e][0] += w * s0;
      o[e][1] += w * s1;
    }
  }
#pragma unroll
  for (int e = 0; e < 4; ++e) {
    const size_t off = (size_t)(bt * 4 + e) * NN + n2;
    if (f32) {
      float2 w = {o[e][0], o[e][1]};
      *(float2*)&((float*)outv)[off] = w;
    } else {
      uint w = (uint)f2bf(o[e][0]) | ((uint)f2bf(o[e][1]) << 16);
      *(uint*)&((ushort*)outv)[off] = w;
    }
  }
}

// ---------------------------------------------------------------------------
extern "C" void kernel_launch(void* const* d_in, const int* in_sizes, int n_in,
                              void* d_out, int out_size, void* d_ws,
                              size_t ws_size, hipStream_t stream) {
  (void)in_sizes; (void)n_in; (void)out_size; (void)ws_size;
  const void* x = d_in[0];
  const ushort* S = (const ushort*)d_in[1];   // raw bytes; dtype detected
  char* ws = (char*)d_ws;
  ushort* xc = (ushort*)(ws + OFF_XC);
  ushort* z1 = (ushort*)(ws + OFF_Z1);
  ushort* z2 = (ushort*)(ws + OFF_Z2);
  ushort* y1 = (ushort*)(ws + OFF_Y1);
  ushort* v1 = (ushort*)(ws + OFF_V1);
  ushort* v2 = (ushort*)(ws + OFF_V2);

  detect_convert<<<1, 256, 0, stream>>>(S, d_in[2], d_in[3], d_in[4], d_in[5],
                                        d_in[6], d_in[7], d_in[8], d_in[9], ws);
  convert_x<<<1024, 256, 0, stream>>>(x, ws, xc);
  // z1 = x @ S ; z2 = z1 @ S   (M=128)
  gemm_s<32, 1, 2><<<dim3(128, 4), 256, 0, stream>>>(xc, S, ws, z1);
  gemm_s<32, 1, 2><<<dim3(128, 4), 256, 0, stream>>>(z1, S, ws, z2);
  combine1<<<256, 256, 0, stream>>>(xc, z1, z2, ws, y1);
  // v1 = y1 @ S ; v2 = v1 @ S  (M=256)
  gemm_s<64, 2, 2><<<dim3(128, 4), 256, 0, stream>>>(y1, S, ws, v1);
  gemm_s<64, 2, 2><<<dim3(128, 4), 256, 0, stream>>>(v1, S, ws, v2);
  combine2<<<512, 256, 0, stream>>>(y1, v1, v2, ws, (void*)d_out);
}

// Round 3
// 757.303 us; speedup vs baseline: 1.1124x; 1.1124x over previous
//
#include <hip/hip_runtime.h>
#include <hip/hip_bf16.h>
#include <math.h>

// Problem dims (fixed): B*T=32, N=8192, F0=4, F1=8, F2=8, K=3, D0=8, D1=4
constexpr int NN = 8192;

typedef short bh8 __attribute__((ext_vector_type(8)));    // 8 bf16 (4 VGPRs)
typedef float fl4 __attribute__((ext_vector_type(4)));    // 4 fp32 acc

__device__ __forceinline__ float bf2f(ushort h) {
  return __uint_as_float(((uint)h) << 16);
}
__device__ __forceinline__ ushort f2bf(float f) {
  uint u = __float_as_uint(f);
  return (ushort)((u + 0x7fffu + ((u >> 16) & 1u)) >> 16);  // RNE
}

// ---- workspace layout (bytes) ----------------------------------------------
constexpr size_t OFF_P  = 16;                    // 412 fp32 canonical params
constexpr size_t OFF_XC = 4096;                  // x bf16 [128][8192]  2 MiB
constexpr size_t OFF_Z1 = OFF_XC + 2097152;      // z1 bf16 [128][8192] 2 MiB
constexpr size_t OFF_Y1 = OFF_Z1 + 2097152;      // y1 bf16 [256][8192] 4 MiB
constexpr size_t OFF_V1 = OFF_Y1 + 4194304;      // v1 bf16 [256][8192] 4 MiB
constexpr size_t OFF_CF = OFF_V1 + 4194304;      // CF fp32 accum       8 MiB
// total ~20 MiB

// param-block offsets (in floats)
constexpr int PO_H1 = 0, PO_B1 = 96, PO_H2 = 104, PO_B2 = 296;
constexpr int PO_W1 = 304, PO_BW1 = 368, PO_W2 = 376, PO_BW2 = 408;

// ---------------------------------------------------------------------------
// detect dtype (fp32 vs bf16) from S's raw bytes; canonicalize params to fp32.
// ---------------------------------------------------------------------------
__global__ __launch_bounds__(256) void detect_convert(
    const ushort* __restrict__ Sraw,
    const void* h1, const void* b1, const void* h2, const void* b2,
    const void* W1, const void* bw1, const void* W2, const void* bw2,
    char* __restrict__ ws) {
  __shared__ int smax[256];
  __shared__ int sflag;
  const int t = threadIdx.x;
  int mx = 0;
  for (int k = 0; k < 32; ++k) {
    ushort u = Sraw[(size_t)(t * 32 + k) * 2];
    int e = (u >> 7) & 0xff;
    mx = mx > e ? mx : e;
  }
  smax[t] = mx;
  __syncthreads();
  for (int s = 128; s > 0; s >>= 1) {
    if (t < s) smax[t] = smax[t] > smax[t + s] ? smax[t] : smax[t + s];
    __syncthreads();
  }
  if (t == 0) {
    sflag = (smax[0] >= 0x90) ? 1 : 0;
    *(int*)ws = sflag;
  }
  __syncthreads();
  const int f32 = sflag;
  float* pb = (float*)(ws + OFF_P);
  const void* ptrs[8] = {h1, b1, h2, b2, W1, bw1, W2, bw2};
  const int offs[8] = {PO_H1, PO_B1, PO_H2, PO_B2, PO_W1, PO_BW1, PO_W2, PO_BW2};
  const int lens[8] = {96, 8, 192, 8, 64, 8, 32, 4};
  for (int idx = t; idx < 412; idx += 256) {
#pragma unroll
    for (int s = 0; s < 8; ++s) {
      if (idx >= offs[s] && idx < offs[s] + lens[s]) {
        const int j = idx - offs[s];
        pb[idx] = f32 ? ((const float*)ptrs[s])[j]
                      : bf2f(((const ushort*)ptrs[s])[j]);
      }
    }
  }
}

// canonicalize x -> bf16 (1,048,576 elements; 4 per thread, 1024 blocks)
__global__ __launch_bounds__(256) void convert_x(const void* __restrict__ xraw,
                                                 const char* __restrict__ wsro,
                                                 ushort* __restrict__ xc) {
  const int f32 = *(const int*)wsro;
  const int i = (blockIdx.x * 256 + threadIdx.x) * 4;
  if (f32) {
    float4 v = *(const float4*)((const float*)xraw + i);
    uint2 o;
    o.x = (uint)f2bf(v.x) | ((uint)f2bf(v.y) << 16);
    o.y = (uint)f2bf(v.z) | ((uint)f2bf(v.w) << 16);
    *(uint2*)&xc[i] = o;
  } else {
    *(uint2*)&xc[i] = *(const uint2*)((const ushort*)xraw + i);
  }
}

// fp32 accum -> bf16 (count/4 threads wide, 4 per thread)
__global__ __launch_bounds__(256) void cvt_f32_bf16(const float* __restrict__ src,
                                                    ushort* __restrict__ dst) {
  const int i = (blockIdx.x * 256 + threadIdx.x) * 4;
  float4 v = *(const float4*)&src[i];
  uint2 o;
  o.x = (uint)f2bf(v.x) | ((uint)f2bf(v.y) << 16);
  o.y = (uint)f2bf(v.z) | ((uint)f2bf(v.w) << 16);
  *(uint2*)&dst[i] = o;
}

// ---------------------------------------------------------------------------
// GEMM with chunked-barrier K-loop + wave-autonomous S streaming.
//   CF[M,N] += A[M,K] @ S[K,N]   (atomicAdd fp32; CF pre-zeroed)
// Block: 512 thr = 8 waves (2m x 4n), BM=128, BN=128, K-chunks of 128.
// Per chunk: barrier; prefetch S-regs (4 iters) + DMA A-tile (LDS, swizzled);
// barrier; 4 barrier-free iters: pack->wave-private LDS transpose->MFMA.
// Grid: (64 n-blocks, M/128, ksplit); k-range per block = kr.
// ---------------------------------------------------------------------------
__global__ __launch_bounds__(512, 4) void gemm_ns(const ushort* __restrict__ A,
                                                  const ushort* __restrict__ Sraw,
                                                  const char* __restrict__ wsro,
                                                  float* __restrict__ CF,
                                                  int kr) {
  __shared__ ushort As[128 * 128];      // 32 KiB, 16 granules/row, XOR swizzled
  __shared__ uint Sbuf[8][512];         // 2 KiB per wave: [32 n][16 kpair uints]
  const int f32 = *(const int*)wsro;
  const int tid = threadIdx.x;
  const int wave = tid >> 6, lane = tid & 63;
  const int lrow = lane & 15, quad = lane >> 4;
  const int m0 = blockIdx.y * 128;
  const int n0 = blockIdx.x * 128;
  const int kc0 = blockIdx.z * kr;
  const int wm = (wave & 1) * 64;       // wave m-range: 64 rows (TM=4)
  const int wn = (wave >> 1) * 32;      // wave n-range: 32 cols (TN=2)
  // S staging map: lane -> kpair p (0..15), col octet g8 (0..24)
  const int p = lane >> 2;
  const int g8 = (lane & 3) * 8;
  uint* Sw = &Sbuf[wave][0];

  fl4 acc[4][2];
#pragma unroll
  for (int i = 0; i < 4; ++i)
#pragma unroll
    for (int j = 0; j < 2; ++j) acc[i][j] = (fl4){0.f, 0.f, 0.f, 0.f};

  for (int kc = kc0; kc < kc0 + kr; kc += 128) {
    __syncthreads();   // all waves done reading As from previous chunk
    // ---- prefetch this chunk's S-stripe into registers (bf16 fast path)
    uint4 r[4][2];
    if (!f32) {
#pragma unroll
      for (int is = 0; is < 4; ++is) {
        const ushort* re = Sraw + (size_t)(kc + is * 32 + 2 * p) * NN + n0 + wn + g8;
        r[is][0] = *(const uint4*)re;
        r[is][1] = *(const uint4*)(re + NN);
      }
    }
    // ---- DMA A chunk: 2048 slots of 16B; slot s: row=s>>4, granule (s&15)^(row&7)
#pragma unroll
    for (int i = 0; i < 4; ++i) {
      const int sb = (wave * 4 + i) * 64;
      const int s = sb + lane;
      const int row = s >> 4;
      const int g = (s & 15) ^ (row & 7);
      const ushort* src = A + (size_t)(m0 + row) * NN + kc + g * 8;
      __builtin_amdgcn_global_load_lds(
          (__attribute__((address_space(1))) void*)src,
          (__attribute__((address_space(3))) void*)&As[sb * 8], 16, 0, 0);
    }
    __syncthreads();   // drains vmcnt: A-tile + S-regs all ready
    // ---- 4 barrier-free iters
#pragma unroll
    for (int is = 0; is < 4; ++is) {
      uint pk[8];
      if (f32) {
        const float* re = (const float*)Sraw +
                          (size_t)(kc + is * 32 + 2 * p) * NN + n0 + wn + g8;
        float4 a0 = *(const float4*)re;
        float4 a1 = *(const float4*)(re + 4);
        float4 b0 = *(const float4*)(re + NN);
        float4 b1 = *(const float4*)(re + NN + 4);
        pk[0] = (uint)f2bf(a0.x) | ((uint)f2bf(b0.x) << 16);
        pk[1] = (uint)f2bf(a0.y) | ((uint)f2bf(b0.y) << 16);
        pk[2] = (uint)f2bf(a0.z) | ((uint)f2bf(b0.z) << 16);
        pk[3] = (uint)f2bf(a0.w) | ((uint)f2bf(b0.w) << 16);
        pk[4] = (uint)f2bf(a1.x) | ((uint)f2bf(b1.x) << 16);
        pk[5] = (uint)f2bf(a1.y) | ((uint)f2bf(b1.y) << 16);
        pk[6] = (uint)f2bf(a1.z) | ((uint)f2bf(b1.z) << 16);
        pk[7] = (uint)f2bf(a1.w) | ((uint)f2bf(b1.w) << 16);
      } else {
        const ushort* ap = (const ushort*)&r[is][0];
        const ushort* bp = (const ushort*)&r[is][1];
#pragma unroll
        for (int j = 0; j < 8; ++j) pk[j] = (uint)ap[j] | ((uint)bp[j] << 16);
      }
      // wave-private transpose: n-row nl gets kpair p at pos (p>>2)^swz(nl), +(p&3)
#pragma unroll
      for (int j = 0; j < 8; ++j) {
        const int jj = j ^ (lane & 1);            // spread n-parity across lanes
        const int nl = g8 + jj;
        const int swz = ((nl >> 1) & 3) ^ ((nl >> 3) & 3);
        Sw[nl * 16 + (((p >> 2) ^ swz) * 4) + (p & 3)] = pk[jj];
      }
      bh8 af[4], bf[2];
#pragma unroll
      for (int i = 0; i < 4; ++i) {
        const int row = wm + i * 16 + lrow;
        const int gg = (is * 4 + quad) ^ (row & 7);
        af[i] = *(const bh8*)&As[row * 128 + gg * 8];
      }
#pragma unroll
      for (int j = 0; j < 2; ++j) {
        const int nl = j * 16 + lrow;
        const int swz = ((nl >> 1) & 3) ^ ((nl >> 3) & 3);
        bf[j] = *(const bh8*)&Sw[nl * 16 + ((quad ^ swz) * 4)];
      }
#pragma unroll
      for (int i = 0; i < 4; ++i)
#pragma unroll
        for (int j = 0; j < 2; ++j)
          acc[i][j] = __builtin_amdgcn_mfma_f32_16x16x32_bf16(af[i], bf[j],
                                                              acc[i][j], 0, 0, 0);
    }
  }
  // ---- epilogue: atomic accumulate (C/D layout col=lane&15, row=quad*4+reg)
#pragma unroll
  for (int i = 0; i < 4; ++i)
#pragma unroll
    for (int j = 0; j < 2; ++j)
#pragma unroll
      for (int rr = 0; rr < 4; ++rr) {
        const int row = m0 + wm + i * 16 + quad * 4 + rr;
        const int col = n0 + wn + j * 16 + lrow;
        atomicAdd(&CF[(size_t)row * NN + col], acc[i][j][rr]);
      }
}

// ---------------------------------------------------------------------------
// combine1: y1[bt,g,n] = tanh(b1[g] + sum_{k,f} h1[g,k,f] * z_k[bt,f,n])
// taps: z0=xc (bf16), z1 (bf16), z2 = CF (fp32). 4 nodes per thread.
// ---------------------------------------------------------------------------
__global__ __launch_bounds__(256) void combine1(const ushort* __restrict__ xc,
                                                const ushort* __restrict__ z1,
                                                const float* __restrict__ z2f,
                                                const char* __restrict__ wsro,
                                                ushort* __restrict__ y1) {
  const float* pb = (const float*)(wsro + OFF_P);
  __shared__ float hs[96], bs[8];
  const int t = threadIdx.x;
  if (t < 96) hs[t] = pb[PO_H1 + t];
  if (t < 8) bs[t] = pb[PO_B1 + t];
  __syncthreads();
  const int idx = blockIdx.x * 256 + t;
  const int bt = idx >> 11;
  const int n4 = (idx & 2047) * 4;
  float acc[8][4];
#pragma unroll
  for (int g = 0; g < 8; ++g)
#pragma unroll
    for (int v = 0; v < 4; ++v) acc[g][v] = bs[g];
#pragma unroll
  for (int k = 0; k < 3; ++k)
#pragma unroll
    for (int f = 0; f < 4; ++f) {
      const size_t off = (size_t)(bt * 4 + f) * NN + n4;
      float val[4];
      if (k == 2) {
        float4 w = *(const float4*)&z2f[off];
        val[0] = w.x; val[1] = w.y; val[2] = w.z; val[3] = w.w;
      } else {
        const ushort* pp = (k == 0) ? xc : z1;
        uint2 w = *(const uint2*)&pp[off];
        val[0] = bf2f(w.x & 0xffff); val[1] = bf2f(w.x >> 16);
        val[2] = bf2f(w.y & 0xffff); val[3] = bf2f(w.y >> 16);
      }
#pragma unroll
      for (int g = 0; g < 8; ++g) {
        const float hw = hs[(g * 3 + k) * 4 + f];
#pragma unroll
        for (int v = 0; v < 4; ++v) acc[g][v] += hw * val[v];
      }
    }
#pragma unroll
  for (int g = 0; g < 8; ++g) {
    ushort o[4];
#pragma unroll
    for (int v = 0; v < 4; ++v) o[v] = f2bf(tanhf(acc[g][v]));
    uint2 w;
    w.x = (uint)o[0] | ((uint)o[1] << 16);
    w.y = (uint)o[2] | ((uint)o[3] << 16);
    *(uint2*)&y1[(size_t)(bt * 8 + g) * NN + n4] = w;
  }
}

// ---------------------------------------------------------------------------
// combine2: y2 = tanh(b2 + sum h2*{y1,v1,v2}); readout W1/tanh/W2; v2 = CF fp32.
// ---------------------------------------------------------------------------
__global__ __launch_bounds__(256) void combine2(const ushort* __restrict__ y1,
                                                const ushort* __restrict__ v1,
                                                const float* __restrict__ v2f,
                                                const char* __restrict__ wsro,
                                                void* __restrict__ outv) {
  const float* pb = (const float*)(wsro + OFF_P);
  const int f32 = *(const int*)wsro;
  __shared__ float h2s[192], W1s[64], W2s[32], b2s[8], bw1s[8], bw2s[4];
  const int t = threadIdx.x;
  if (t < 192) h2s[t] = pb[PO_H2 + t];
  if (t < 64) W1s[t] = pb[PO_W1 + t];
  if (t < 32) W2s[t] = pb[PO_W2 + t];
  if (t < 8) { b2s[t] = pb[PO_B2 + t]; bw1s[t] = pb[PO_BW1 + t]; }
  if (t < 4) bw2s[t] = pb[PO_BW2 + t];
  __syncthreads();
  const int idx = blockIdx.x * 256 + t;
  const int bt = idx >> 12;
  const int n2 = (idx & 4095) * 2;
  float acc[8][2];
#pragma unroll
  for (int g = 0; g < 8; ++g) { acc[g][0] = b2s[g]; acc[g][1] = b2s[g]; }
#pragma unroll
  for (int k = 0; k < 3; ++k)
#pragma unroll
    for (int g1 = 0; g1 < 8; ++g1) {
      const size_t off = (size_t)(bt * 8 + g1) * NN + n2;
      float v0, v1v;
      if (k == 2) {
        float2 w = *(const float2*)&v2f[off];
        v0 = w.x; v1v = w.y;
      } else {
        const ushort* pp = (k == 0) ? y1 : v1;
        uint w = *(const uint*)&pp[off];
        v0 = bf2f(w & 0xffff); v1v = bf2f(w >> 16);
      }
#pragma unroll
      for (int g2 = 0; g2 < 8; ++g2) {
        const float hw = h2s[(g2 * 3 + k) * 8 + g1];
        acc[g2][0] += hw * v0;
        acc[g2][1] += hw * v1v;
      }
    }
#pragma unroll
  for (int g = 0; g < 8; ++g) {
    acc[g][0] = tanhf(acc[g][0]);
    acc[g][1] = tanhf(acc[g][1]);
  }
  float o[4][2];
#pragma unroll
  for (int e = 0; e < 4; ++e) { o[e][0] = bw2s[e]; o[e][1] = bw2s[e]; }
#pragma unroll
  for (int d = 0; d < 8; ++d) {
    float s0 = bw1s[d], s1 = bw1s[d];
#pragma unroll
    for (int f = 0; f < 8; ++f) {
      const float w = W1s[d * 8 + f];
      s0 += w * acc[f][0];
      s1 += w * acc[f][1];
    }
    s0 = tanhf(s0);
    s1 = tanhf(s1);
#pragma unroll
    for (int e = 0; e < 4; ++e) {
      const float w = W2s[e * 8 + d];
      o[e][0] += w * s0;
      o[e][1] += w * s1;
    }
  }
#pragma unroll
  for (int e = 0; e < 4; ++e) {
    const size_t off = (size_t)(bt * 4 + e) * NN + n2;
    if (f32) {
      float2 w = {o[e][0], o[e][1]};
      *(float2*)&((float*)outv)[off] = w;
    } else {
      uint w = (uint)f2bf(o[e][0]) | ((uint)f2bf(o[e][1]) << 16);
      *(uint*)&((ushort*)outv)[off] = w;
    }
  }
}

// ---------------------------------------------------------------------------
extern "C" void kernel_launch(void* const* d_in, const int* in_sizes, int n_in,
                              void* d_out, int out_size, void* d_ws,
                              size_t ws_size, hipStream_t stream) {
  (void)in_sizes; (void)n_in; (void)out_size; (void)ws_size;
  const void* x = d_in[0];
  const ushort* S = (const ushort*)d_in[1];   // raw bytes; dtype detected
  char* ws = (char*)d_ws;
  ushort* xc = (ushort*)(ws + OFF_XC);
  ushort* z1 = (ushort*)(ws + OFF_Z1);
  ushort* y1 = (ushort*)(ws + OFF_Y1);
  ushort* v1 = (ushort*)(ws + OFF_V1);
  float* CF = (float*)(ws + OFF_CF);

  detect_convert<<<1, 256, 0, stream>>>(S, d_in[2], d_in[3], d_in[4], d_in[5],
                                        d_in[6], d_in[7], d_in[8], d_in[9], ws);
  convert_x<<<1024, 256, 0, stream>>>(x, ws, xc);

  // z1 = x @ S   (M=128, ksplit 8)
  hipMemsetAsync(CF, 0, 4194304, stream);
  gemm_ns<<<dim3(64, 1, 8), 512, 0, stream>>>(xc, S, ws, CF, 1024);
  cvt_f32_bf16<<<1024, 256, 0, stream>>>(CF, z1);

  // z2 = z1 @ S  (M=128, ksplit 8) -> CF, consumed by combine1
  hipMemsetAsync(CF, 0, 4194304, stream);
  gemm_ns<<<dim3(64, 1, 8), 512, 0, stream>>>(z1, S, ws, CF, 1024);
  combine1<<<256, 256, 0, stream>>>(xc, z1, CF, ws, y1);

  // v1 = y1 @ S  (M=256, ksplit 4)
  hipMemsetAsync(CF, 0, 8388608, stream);
  gemm_ns<<<dim3(64, 2, 4), 512, 0, stream>>>(y1, S, ws, CF, 2048);
  cvt_f32_bf16<<<2048, 256, 0, stream>>>(CF, v1);

  // v2 = v1 @ S  (M=256, ksplit 4) -> CF, consumed by combine2
  hipMemsetAsync(CF, 0, 8388608, stream);
  gemm_ns<<<dim3(64, 2, 4), 512, 0, stream>>>(v1, S, ws, CF, 2048);
  combine2<<<512, 256, 0, stream>>>(y1, v1, CF, ws, (void*)d_out);
}

// Round 4
// 651.686 us; speedup vs baseline: 1.2927x; 1.1621x over previous
//
#include <hip/hip_runtime.h>
#include <hip/hip_bf16.h>
#include <math.h>

// Problem dims (fixed): B*T=32, N=8192, F0=4, F1=8, F2=8, K=3, D0=8, D1=4
constexpr int NN = 8192;

typedef short bh8 __attribute__((ext_vector_type(8)));    // 8 bf16 (4 VGPRs)
typedef float fl4 __attribute__((ext_vector_type(4)));    // 4 fp32 acc

__device__ __forceinline__ float bf2f(ushort h) {
  return __uint_as_float(((uint)h) << 16);
}
__device__ __forceinline__ ushort f2bf(float f) {
  uint u = __float_as_uint(f);
  return (ushort)((u + 0x7fffu + ((u >> 16) & 1u)) >> 16);  // RNE
}

// ---- workspace layout (bytes); ws_size >= 1 GiB (poison-fill evidence) ------
constexpr size_t OFF_P  = 16;                    // 412 fp32 canonical params
constexpr size_t OFF_XC = 4096;                  // x bf16 [128][8192]  2 MiB
constexpr size_t OFF_Z1 = OFF_XC + 2097152;      // z1 bf16 [128][8192] 2 MiB
constexpr size_t OFF_Y1 = OFF_Z1 + 2097152;      // y1 bf16 [256][8192] 4 MiB
constexpr size_t OFF_V1 = OFF_Y1 + 4194304;      // v1 bf16 [256][8192] 4 MiB
constexpr size_t OFF_CF = OFF_V1 + 4194304;      // CF fp32 accum       8 MiB
constexpr size_t OFF_ST = 33554432;              // St bf16 [8192][8192] 128 MiB
// total ~160 MiB

// param-block offsets (in floats)
constexpr int PO_H1 = 0, PO_B1 = 96, PO_H2 = 104, PO_B2 = 296;
constexpr int PO_W1 = 304, PO_BW1 = 368, PO_W2 = 376, PO_BW2 = 408;

// ---------------------------------------------------------------------------
// detect dtype (fp32 vs bf16) from S's raw bytes; canonicalize params to fp32.
// ---------------------------------------------------------------------------
__global__ __launch_bounds__(256) void detect_convert(
    const ushort* __restrict__ Sraw,
    const void* h1, const void* b1, const void* h2, const void* b2,
    const void* W1, const void* bw1, const void* W2, const void* bw2,
    char* __restrict__ ws) {
  __shared__ int smax[256];
  __shared__ int sflag;
  const int t = threadIdx.x;
  int mx = 0;
  for (int k = 0; k < 32; ++k) {
    ushort u = Sraw[(size_t)(t * 32 + k) * 2];
    int e = (u >> 7) & 0xff;
    mx = mx > e ? mx : e;
  }
  smax[t] = mx;
  __syncthreads();
  for (int s = 128; s > 0; s >>= 1) {
    if (t < s) smax[t] = smax[t] > smax[t + s] ? smax[t] : smax[t + s];
    __syncthreads();
  }
  if (t == 0) {
    sflag = (smax[0] >= 0x90) ? 1 : 0;
    *(int*)ws = sflag;
  }
  __syncthreads();
  const int f32 = sflag;
  float* pb = (float*)(ws + OFF_P);
  const void* ptrs[8] = {h1, b1, h2, b2, W1, bw1, W2, bw2};
  const int offs[8] = {PO_H1, PO_B1, PO_H2, PO_B2, PO_W1, PO_BW1, PO_W2, PO_BW2};
  const int lens[8] = {96, 8, 192, 8, 64, 8, 32, 4};
  for (int idx = t; idx < 412; idx += 256) {
#pragma unroll
    for (int s = 0; s < 8; ++s) {
      if (idx >= offs[s] && idx < offs[s] + lens[s]) {
        const int j = idx - offs[s];
        pb[idx] = f32 ? ((const float*)ptrs[s])[j]
                      : bf2f(((const ushort*)ptrs[s])[j]);
      }
    }
  }
}

// canonicalize x -> bf16 (1,048,576 elements; 4 per thread, 1024 blocks)
__global__ __launch_bounds__(256) void convert_x(const void* __restrict__ xraw,
                                                 const char* __restrict__ wsro,
                                                 ushort* __restrict__ xc) {
  const int f32 = *(const int*)wsro;
  const int i = (blockIdx.x * 256 + threadIdx.x) * 4;
  if (f32) {
    float4 v = *(const float4*)((const float*)xraw + i);
    uint2 o;
    o.x = (uint)f2bf(v.x) | ((uint)f2bf(v.y) << 16);
    o.y = (uint)f2bf(v.z) | ((uint)f2bf(v.w) << 16);
    *(uint2*)&xc[i] = o;
  } else {
    *(uint2*)&xc[i] = *(const uint2*)((const ushort*)xraw + i);
  }
}

// fp32 accum -> bf16 (count/4 threads wide, 4 per thread)
__global__ __launch_bounds__(256) void cvt_f32_bf16(const float* __restrict__ src,
                                                    ushort* __restrict__ dst) {
  const int i = (blockIdx.x * 256 + threadIdx.x) * 4;
  float4 v = *(const float4*)&src[i];
  uint2 o;
  o.x = (uint)f2bf(v.x) | ((uint)f2bf(v.y) << 16);
  o.y = (uint)f2bf(v.z) | ((uint)f2bf(v.w) << 16);
  *(uint2*)&dst[i] = o;
}

// ---------------------------------------------------------------------------
// Transpose S[k][n] -> St[n][k] (bf16 out), 64x64 tiles, k-pairs packed in
// uint LDS cells, stride 33. Handles fp32 or bf16 S per detected flag.
// ---------------------------------------------------------------------------
__global__ __launch_bounds__(256) void transpose_k(const ushort* __restrict__ Sraw,
                                                   const char* __restrict__ wsro,
                                                   ushort* __restrict__ St) {
  __shared__ uint tileU[64][33];
  const int f32 = *(const int*)wsro;
  const int t = threadIdx.x;
  const int tn = blockIdx.x * 64;   // node (output-row) tile
  const int tk = blockIdx.y * 64;   // k tile
  {
    const int kp = t >> 3;          // 0..31 k-pair
    const int c  = (t & 7) * 8;     // 0..56 node offset
    if (f32) {
      const float* r0 = (const float*)Sraw + (size_t)(tk + 2 * kp) * NN + tn + c;
      float4 a0 = *(const float4*)r0;
      float4 a1 = *(const float4*)(r0 + 4);
      float4 b0 = *(const float4*)(r0 + NN);
      float4 b1 = *(const float4*)(r0 + NN + 4);
      tileU[c + 0][kp] = (uint)f2bf(a0.x) | ((uint)f2bf(b0.x) << 16);
      tileU[c + 1][kp] = (uint)f2bf(a0.y) | ((uint)f2bf(b0.y) << 16);
      tileU[c + 2][kp] = (uint)f2bf(a0.z) | ((uint)f2bf(b0.z) << 16);
      tileU[c + 3][kp] = (uint)f2bf(a0.w) | ((uint)f2bf(b0.w) << 16);
      tileU[c + 4][kp] = (uint)f2bf(a1.x) | ((uint)f2bf(b1.x) << 16);
      tileU[c + 5][kp] = (uint)f2bf(a1.y) | ((uint)f2bf(b1.y) << 16);
      tileU[c + 6][kp] = (uint)f2bf(a1.z) | ((uint)f2bf(b1.z) << 16);
      tileU[c + 7][kp] = (uint)f2bf(a1.w) | ((uint)f2bf(b1.w) << 16);
    } else {
      const ushort* r0 = Sraw + (size_t)(tk + 2 * kp) * NN + tn + c;
      uint4 ua = *(const uint4*)r0;
      uint4 ub = *(const uint4*)(r0 + NN);
      const ushort* ap = (const ushort*)&ua;
      const ushort* bp = (const ushort*)&ub;
#pragma unroll
      for (int j = 0; j < 8; ++j)
        tileU[c + j][kp] = (uint)ap[j] | ((uint)bp[j] << 16);
    }
  }
  __syncthreads();
  {
    const int n = t >> 2;           // 0..63
#pragma unroll
    for (int it = 0; it < 2; ++it) {
      const int q = (t & 3) + 4 * it;   // 0..7 (8 k-elements each)
      uint4 w;
      w.x = tileU[n][q * 4 + 0];
      w.y = tileU[n][q * 4 + 1];
      w.z = tileU[n][q * 4 + 2];
      w.w = tileU[n][q * 4 + 3];
      *(uint4*)&St[(size_t)(tn + n) * NN + tk + q * 8] = w;
    }
  }
}

// ---------------------------------------------------------------------------
// GEMM: CF[M,N] += A[M,K] @ St[N,K]^T  (both operands canonical bf16,
// k-contiguous). m97-style: global_load_lds(16B) staging with XOR-granule
// swizzle, software-pipelined double-buffered BK=64 chunks, one barrier per
// chunk (prefetch issued BEFORE compute so the barrier's vmcnt(0) drain lands
// after a full compute phase of flight). 512 thr = 8 waves (2m x 4n),
// BM=BN=128; grid (64, M/128, ksplit); atomicAdd fp32 epilogue (CF zeroed).
// ---------------------------------------------------------------------------
template <int KR>
__global__ __launch_bounds__(512, 4) void gemm_t(const ushort* __restrict__ A,
                                                 const ushort* __restrict__ St,
                                                 float* __restrict__ CF) {
  __shared__ ushort As[2][128 * 64];   // 16 KiB each
  __shared__ ushort Bs[2][128 * 64];
  const int tid = threadIdx.x;
  const int wave = tid >> 6, lane = tid & 63;
  const int lrow = lane & 15, quad = lane >> 4;
  const int m0 = blockIdx.y * 128;
  const int n0 = blockIdx.x * 128;
  const int kc0 = blockIdx.z * KR;
  const int wm = (wave & 1) * 64;       // TM=4
  const int wn = (wave >> 1) * 32;      // TN=2

  // staging map (proven round 2): slot s=row*8+gs holds granule g=gs^(row&7)
  const int s0i = (wave * 2) * 64 + lane;
  const int s1i = (wave * 2 + 1) * 64 + lane;
  const int r0 = s0i >> 3, g0 = (s0i & 7) ^ (r0 & 7);
  const int r1 = s1i >> 3, g1 = (s1i & 7) ^ (r1 & 7);
  const ushort* a0p = A + (size_t)(m0 + r0) * NN + g0 * 8;
  const ushort* a1p = A + (size_t)(m0 + r1) * NN + g1 * 8;
  const ushort* b0p = St + (size_t)(n0 + r0) * NN + g0 * 8;
  const ushort* b1p = St + (size_t)(n0 + r1) * NN + g1 * 8;

  fl4 acc[4][2];
#pragma unroll
  for (int i = 0; i < 4; ++i)
#pragma unroll
    for (int j = 0; j < 2; ++j) acc[i][j] = (fl4){0.f, 0.f, 0.f, 0.f};

#define STAGE(buf, kc)                                                         \
  {                                                                            \
    __builtin_amdgcn_global_load_lds(                                          \
        (__attribute__((address_space(1))) void*)(a0p + (kc)),                 \
        (__attribute__((address_space(3))) void*)&As[buf][(wave * 2) * 512],   \
        16, 0, 0);                                                             \
    __builtin_amdgcn_global_load_lds(                                          \
        (__attribute__((address_space(1))) void*)(a1p + (kc)),                 \
        (__attribute__((address_space(3))) void*)&As[buf][(wave * 2 + 1) * 512],\
        16, 0, 0);                                                             \
    __builtin_amdgcn_global_load_lds(                                          \
        (__attribute__((address_space(1))) void*)(b0p + (kc)),                 \
        (__attribute__((address_space(3))) void*)&Bs[buf][(wave * 2) * 512],   \
        16, 0, 0);                                                             \
    __builtin_amdgcn_global_load_lds(                                          \
        (__attribute__((address_space(1))) void*)(b1p + (kc)),                 \
        (__attribute__((address_space(3))) void*)&Bs[buf][(wave * 2 + 1) * 512],\
        16, 0, 0);                                                             \
  }

#define COMPUTE(buf)                                                           \
  {                                                                            \
    _Pragma("unroll")                                                          \
    for (int is = 0; is < 2; ++is) {                                           \
      bh8 af[4], bf[2];                                                        \
      const int G = is * 4 + quad;                                             \
      _Pragma("unroll")                                                        \
      for (int i = 0; i < 4; ++i) {                                            \
        const int row = wm + i * 16 + lrow;                                    \
        af[i] = *(const bh8*)&As[buf][row * 64 + ((G ^ (row & 7)) * 8)];       \
      }                                                                        \
      _Pragma("unroll")                                                        \
      for (int j = 0; j < 2; ++j) {                                            \
        const int row = wn + j * 16 + lrow;                                    \
        bf[j] = *(const bh8*)&Bs[buf][row * 64 + ((G ^ (row & 7)) * 8)];       \
      }                                                                        \
      _Pragma("unroll")                                                        \
      for (int i = 0; i < 4; ++i)                                              \
        _Pragma("unroll")                                                      \
        for (int j = 0; j < 2; ++j)                                            \
          acc[i][j] = __builtin_amdgcn_mfma_f32_16x16x32_bf16(af[i], bf[j],    \
                                                              acc[i][j], 0, 0, 0); \
    }                                                                          \
  }

  STAGE(0, kc0)
  const int kend = kc0 + KR;
#pragma unroll 1
  for (int kc = kc0; kc < kend; kc += 128) {
    __syncthreads();                 // drains DMA for buf0 chunk kc
    STAGE(1, kc + 64)                // flies during compute of buf0
    COMPUTE(0)
    __syncthreads();                 // drains DMA for buf1 chunk kc+64
    if (kc + 128 < kend) STAGE(0, kc + 128)
    COMPUTE(1)
  }
#undef STAGE
#undef COMPUTE

  // epilogue: C/D layout col=lane&15, row=quad*4+reg; atomic ksplit reduce
#pragma unroll
  for (int i = 0; i < 4; ++i)
#pragma unroll
    for (int j = 0; j < 2; ++j)
#pragma unroll
      for (int rr = 0; rr < 4; ++rr) {
        const int row = m0 + wm + i * 16 + quad * 4 + rr;
        const int col = n0 + wn + j * 16 + lrow;
        atomicAdd(&CF[(size_t)row * NN + col], acc[i][j][rr]);
      }
}

// ---------------------------------------------------------------------------
// combine1: y1[bt,g,n] = tanh(b1[g] + sum_{k,f} h1[g,k,f] * z_k[bt,f,n])
// taps: z0=xc (bf16), z1 (bf16), z2 = CF (fp32). 4 nodes per thread.
// ---------------------------------------------------------------------------
__global__ __launch_bounds__(256) void combine1(const ushort* __restrict__ xc,
                                                const ushort* __restrict__ z1,
                                                const float* __restrict__ z2f,
                                                const char* __restrict__ wsro,
                                                ushort* __restrict__ y1) {
  const float* pb = (const float*)(wsro + OFF_P);
  __shared__ float hs[96], bs[8];
  const int t = threadIdx.x;
  if (t < 96) hs[t] = pb[PO_H1 + t];
  if (t < 8) bs[t] = pb[PO_B1 + t];
  __syncthreads();
  const int idx = blockIdx.x * 256 + t;
  const int bt = idx >> 11;
  const int n4 = (idx & 2047) * 4;
  float acc[8][4];
#pragma unroll
  for (int g = 0; g < 8; ++g)
#pragma unroll
    for (int v = 0; v < 4; ++v) acc[g][v] = bs[g];
#pragma unroll
  for (int k = 0; k < 3; ++k)
#pragma unroll
    for (int f = 0; f < 4; ++f) {
      const size_t off = (size_t)(bt * 4 + f) * NN + n4;
      float val[4];
      if (k == 2) {
        float4 w = *(const float4*)&z2f[off];
        val[0] = w.x; val[1] = w.y; val[2] = w.z; val[3] = w.w;
      } else {
        const ushort* pp = (k == 0) ? xc : z1;
        uint2 w = *(const uint2*)&pp[off];
        val[0] = bf2f(w.x & 0xffff); val[1] = bf2f(w.x >> 16);
        val[2] = bf2f(w.y & 0xffff); val[3] = bf2f(w.y >> 16);
      }
#pragma unroll
      for (int g = 0; g < 8; ++g) {
        const float hw = hs[(g * 3 + k) * 4 + f];
#pragma unroll
        for (int v = 0; v < 4; ++v) acc[g][v] += hw * val[v];
      }
    }
#pragma unroll
  for (int g = 0; g < 8; ++g) {
    ushort o[4];
#pragma unroll
    for (int v = 0; v < 4; ++v) o[v] = f2bf(tanhf(acc[g][v]));
    uint2 w;
    w.x = (uint)o[0] | ((uint)o[1] << 16);
    w.y = (uint)o[2] | ((uint)o[3] << 16);
    *(uint2*)&y1[(size_t)(bt * 8 + g) * NN + n4] = w;
  }
}

// ---------------------------------------------------------------------------
// combine2: y2 = tanh(b2 + sum h2*{y1,v1,v2}); readout W1/tanh/W2; v2 = CF fp32.
// ---------------------------------------------------------------------------
__global__ __launch_bounds__(256) void combine2(const ushort* __restrict__ y1,
                                                const ushort* __restrict__ v1,
                                                const float* __restrict__ v2f,
                                                const char* __restrict__ wsro,
                                                void* __restrict__ outv) {
  const float* pb = (const float*)(wsro + OFF_P);
  const int f32 = *(const int*)wsro;
  __shared__ float h2s[192], W1s[64], W2s[32], b2s[8], bw1s[8], bw2s[4];
  const int t = threadIdx.x;
  if (t < 192) h2s[t] = pb[PO_H2 + t];
  if (t < 64) W1s[t] = pb[PO_W1 + t];
  if (t < 32) W2s[t] = pb[PO_W2 + t];
  if (t < 8) { b2s[t] = pb[PO_B2 + t]; bw1s[t] = pb[PO_BW1 + t]; }
  if (t < 4) bw2s[t] = pb[PO_BW2 + t];
  __syncthreads();
  const int idx = blockIdx.x * 256 + t;
  const int bt = idx >> 12;
  const int n2 = (idx & 4095) * 2;
  float acc[8][2];
#pragma unroll
  for (int g = 0; g < 8; ++g) { acc[g][0] = b2s[g]; acc[g][1] = b2s[g]; }
#pragma unroll
  for (int k = 0; k < 3; ++k)
#pragma unroll
    for (int g1 = 0; g1 < 8; ++g1) {
      const size_t off = (size_t)(bt * 8 + g1) * NN + n2;
      float v0, v1v;
      if (k == 2) {
        float2 w = *(const float2*)&v2f[off];
        v0 = w.x; v1v = w.y;
      } else {
        const ushort* pp = (k == 0) ? y1 : v1;
        uint w = *(const uint*)&pp[off];
        v0 = bf2f(w & 0xffff); v1v = bf2f(w >> 16);
      }
#pragma unroll
      for (int g2 = 0; g2 < 8; ++g2) {
        const float hw = h2s[(g2 * 3 + k) * 8 + g1];
        acc[g2][0] += hw * v0;
        acc[g2][1] += hw * v1v;
      }
    }
#pragma unroll
  for (int g = 0; g < 8; ++g) {
    acc[g][0] = tanhf(acc[g][0]);
    acc[g][1] = tanhf(acc[g][1]);
  }
  float o[4][2];
#pragma unroll
  for (int e = 0; e < 4; ++e) { o[e][0] = bw2s[e]; o[e][1] = bw2s[e]; }
#pragma unroll
  for (int d = 0; d < 8; ++d) {
    float s0 = bw1s[d], s1 = bw1s[d];
#pragma unroll
    for (int f = 0; f < 8; ++f) {
      const float w = W1s[d * 8 + f];
      s0 += w * acc[f][0];
      s1 += w * acc[f][1];
    }
    s0 = tanhf(s0);
    s1 = tanhf(s1);
#pragma unroll
    for (int e = 0; e < 4; ++e) {
      const float w = W2s[e * 8 + d];
      o[e][0] += w * s0;
      o[e][1] += w * s1;
    }
  }
#pragma unroll
  for (int e = 0; e < 4; ++e) {
    const size_t off = (size_t)(bt * 4 + e) * NN + n2;
    if (f32) {
      float2 w = {o[e][0], o[e][1]};
      *(float2*)&((float*)outv)[off] = w;
    } else {
      uint w = (uint)f2bf(o[e][0]) | ((uint)f2bf(o[e][1]) << 16);
      *(uint*)&((ushort*)outv)[off] = w;
    }
  }
}

// ---------------------------------------------------------------------------
extern "C" void kernel_launch(void* const* d_in, const int* in_sizes, int n_in,
                              void* d_out, int out_size, void* d_ws,
                              size_t ws_size, hipStream_t stream) {
  (void)in_sizes; (void)n_in; (void)out_size; (void)ws_size;
  const void* x = d_in[0];
  const ushort* S = (const ushort*)d_in[1];   // raw bytes; dtype detected
  char* ws = (char*)d_ws;
  ushort* xc = (ushort*)(ws + OFF_XC);
  ushort* z1 = (ushort*)(ws + OFF_Z1);
  ushort* y1 = (ushort*)(ws + OFF_Y1);
  ushort* v1 = (ushort*)(ws + OFF_V1);
  float* CF = (float*)(ws + OFF_CF);
  ushort* St = (ushort*)(ws + OFF_ST);

  detect_convert<<<1, 256, 0, stream>>>(S, d_in[2], d_in[3], d_in[4], d_in[5],
                                        d_in[6], d_in[7], d_in[8], d_in[9], ws);
  convert_x<<<1024, 256, 0, stream>>>(x, ws, xc);
  transpose_k<<<dim3(128, 128), 256, 0, stream>>>(S, ws, St);

  // z1 = x @ S   (M=128, ksplit 8)
  hipMemsetAsync(CF, 0, 4194304, stream);
  gemm_t<1024><<<dim3(64, 1, 8), 512, 0, stream>>>(xc, St, CF);
  cvt_f32_bf16<<<1024, 256, 0, stream>>>(CF, z1);

  // z2 = z1 @ S  (M=128, ksplit 8) -> CF, consumed by combine1
  hipMemsetAsync(CF, 0, 4194304, stream);
  gemm_t<1024><<<dim3(64, 1, 8), 512, 0, stream>>>(z1, St, CF);
  combine1<<<256, 256, 0, stream>>>(xc, z1, CF, ws, y1);

  // v1 = y1 @ S  (M=256, ksplit 4)
  hipMemsetAsync(CF, 0, 8388608, stream);
  gemm_t<2048><<<dim3(64, 2, 4), 512, 0, stream>>>(y1, St, CF);
  cvt_f32_bf16<<<2048, 256, 0, stream>>>(CF, v1);

  // v2 = v1 @ S  (M=256, ksplit 4) -> CF, consumed by combine2
  hipMemsetAsync(CF, 0, 8388608, stream);
  gemm_t<2048><<<dim3(64, 2, 4), 512, 0, stream>>>(v1, St, CF);
  combine2<<<512, 256, 0, stream>>>(y1, v1, CF, ws, (void*)d_out);
}